// Round 6
// baseline (206.209 us; speedup 1.0000x reference)
//
#include <hip/hip_runtime.h>
#include <hip/hip_bf16.h>

// Problem constants (fixed by the reference setup)
#define BGR  128          // graphs
#define NPG  111          // nodes per graph
#define EPG  (NPG*(NPG-1))// 12210 directed edges per graph
#define NTOT (BGR*NPG)    // 14208 nodes
#define TSTR 113          // hs_t row stride (coprime with 32)
#define DPB  14           // dsts per gat block (8 blocks per graph)

// ---------------------------------------------------------------------------
// Fully fused GAT layer: edge-attention (from raw edge_attr), projection,
// reduction-free softmax, aggregation; last layer also fuses global_add_pool
// + final linear + relu via device-scope atomics.
// grid = BGR*8 blocks of 256; block = (graph g, 14-dst slice).
__global__ __launch_bounds__(256, 4) void
gat_fused(const float* __restrict__ xin,   // din1: [NTOT]; else [NTOT*32]
          int din1, int do_relu, int last,
          const float* __restrict__ W,     // [din][32]
          const float* __restrict__ as_w, const float* __restrict__ ad_w,
          const float* __restrict__ We,    // [2][32]
          const float* __restrict__ ae,    // [32]
          const float* __restrict__ ea,    // edge_attr [E][2]
          const float* __restrict__ bias,
          const float* __restrict__ linW, const float* __restrict__ linb,
          float* __restrict__ h_out,
          float* __restrict__ accG, int* __restrict__ cntG,
          float* __restrict__ outp) {
    int g = blockIdx.x >> 3;
    int part = blockIdx.x & 7;
    int t = threadIdx.x;
    int wave = t >> 6, lane = t & 63;
    int c = lane & 31;
    int jb = (part == 0) ? 0 : (14 * part - 1);   // stripe j-base

    __shared__ float stripe[NPG * 15];   // eatt column stripe [s][jj], 6660 B
    __shared__ float scratch[NPG * 32];  // hprev, later coef[16][112] + pw
    __shared__ float hs_t[32 * TSTR];    // transposed h, col 111 zeroed
    __shared__ float Ws[1024];
    __shared__ float ass[NPG], ads[NPG];
    __shared__ float diag[16];
    __shared__ float cv[2];

    // zero pool accumulators for the last layer (ws is poisoned every call)
    if (!last && part == 0 && t == 0) { accG[g] = 0.f; cntG[g] = 0; }

    // ---- phase A: c = We @ ae ----
    if (t < 64) {
        int r = t >> 5, k = t & 31;
        float p = We[r * 32 + k] * ae[k];
        for (int off = 1; off < 32; off <<= 1) p += __shfl_xor(p, off);
        if (k == 0) cv[r] = p;
    }
    __syncthreads();
    float c0 = cv[0], c1 = cv[1];

    // ---- phase B: stage stripe + input features + weights ----
    {
        const float2* eg2 = (const float2*)ea + (size_t)g * EPG;
        for (int idx = t; idx < NPG * 15; idx += 256) {
            int s = idx / 15, jj = idx - s * 15;
            int j = jb + jj;
            float v = 0.f;
            if (j <= 109) {
                float2 e2 = eg2[s * 110 + j];
                v = c0 * e2.x + c1 * e2.y;
            }
            stripe[idx] = v;
        }
    }
    if (din1) {
        if (t < NPG) scratch[t] = xin[g * NPG + t];
        if (t < 32) Ws[t] = W[t];
    } else {
        const float4* src = (const float4*)(xin + (size_t)g * NPG * 32);
        for (int i = t; i < NPG * 8; i += 256) ((float4*)scratch)[i] = src[i];
        for (int i = t; i < 1024; i += 256) Ws[i] = W[i];
    }
    if (t < 32) hs_t[t * TSTR + 111] = 0.f;
    __syncthreads();

    // ---- phase C: proj -> hs_t (transposed), zero shuffles ----
    int il = t >> 5;                      // 0..7 node slot
    for (int pass = 0; pass < 14; pass++) {
        int s = pass * 8 + il;
        if (s < NPG) {
            float hv;
            if (din1) {
                hv = scratch[s] * Ws[c];
            } else {
                float acc = 0.f;
                const float4* row = (const float4*)&scratch[s * 32];
                #pragma unroll
                for (int k4 = 0; k4 < 8; k4++) {
                    float4 xv = row[k4];
                    if (do_relu) {
                        xv.x = fmaxf(xv.x, 0.f); xv.y = fmaxf(xv.y, 0.f);
                        xv.z = fmaxf(xv.z, 0.f); xv.w = fmaxf(xv.w, 0.f);
                    }
                    acc += xv.x * Ws[(k4 * 4 + 0) * 32 + c]
                         + xv.y * Ws[(k4 * 4 + 1) * 32 + c]
                         + xv.z * Ws[(k4 * 4 + 2) * 32 + c]
                         + xv.w * Ws[(k4 * 4 + 3) * 32 + c];
                }
                hv = acc;
            }
            hs_t[c * TSTR + s] = hv;
        }
    }
    __syncthreads();   // hs_t complete; hprev (scratch) now dead

    // ---- phase D: as/ad dots (t<111) + self-loop diagonal (t in [112,126)) ----
    if (t < NPG) {
        float sa = 0.f, sd = 0.f;
        #pragma unroll 8
        for (int cc = 0; cc < 32; cc++) {
            float hv = hs_t[cc * TSTR + t];
            sa += hv * as_w[cc];
            sd += hv * ad_w[cc];
        }
        ass[t] = sa; ads[t] = sd;
    } else if (t >= 112 && t < 112 + DPB) {
        int dl = t - 112;
        int d = part * DPB + dl;
        float sum = 0.f;
        if (d < NPG) {
            for (int s = 0; s < NPG; s++) {
                if (s != d) {
                    int col = d - (d > s ? 1 : 0) - jb;
                    sum += stripe[s * 15 + col];
                }
            }
        }
        diag[dl] = sum * (1.f / 110.f);
    }
    __syncthreads();

    // ---- scores: pure elementwise exp(leaky(.)), coef overlays scratch ----
    float* coef = scratch;               // [16][112], floats 0..1791
    bool actp[4];
    int sB = lane + 64;
    #pragma unroll
    for (int p = 0; p < 4; p++) {
        int dl = wave * 4 + p;
        int d = part * DPB + dl;
        bool act = (dl < DPB) && (d < NPG);
        actp[p] = act;
        int row = dl * 112;
        if (act) {
            float add = ads[d];
            {
                int col = d - (d > lane ? 1 : 0) - jb;
                col = (col > 14) ? 14 : col;
                float ev = (lane == d) ? diag[dl] : stripe[lane * 15 + col];
                float a1 = ass[lane] + add + ev;
                a1 = (a1 > 0.f) ? a1 : 0.2f * a1;
                coef[row + lane] = __expf(a1);
            }
            if (sB < 112) {
                float e2 = 0.f;
                if (sB < NPG) {
                    int col = d - (d > sB ? 1 : 0) - jb;
                    col = (col > 14) ? 14 : col;
                    float ev = (sB == d) ? diag[dl] : stripe[sB * 15 + col];
                    float a2 = ass[sB] + add + ev;
                    a2 = (a2 > 0.f) ? a2 : 0.2f * a2;
                    e2 = __expf(a2);
                }
                coef[row + sB] = e2;
            }
        } else {
            coef[row + lane] = 0.f;
            if (sB < 112) coef[row + sB] = 0.f;
        }
    }
    // per-wave coef: same-wave LDS write->read is ordered; no barrier needed

    // ---- aggregation + denominator ----
    int sbase = (lane >> 5) * 56;        // half 0: s 0..55, half 1: 56..111
    const float* c0p = &coef[(wave * 4 + 0) * 112];
    const float* c1p = &coef[(wave * 4 + 1) * 112];
    const float* c2p = &coef[(wave * 4 + 2) * 112];
    const float* c3p = &coef[(wave * 4 + 3) * 112];
    float acc0 = 0.f, acc1 = 0.f, acc2 = 0.f, acc3 = 0.f;
    float den0 = 0.f, den1 = 0.f, den2 = 0.f, den3 = 0.f;
    #pragma unroll
    for (int j4 = 0; j4 < 56; j4 += 4) {
        int s4 = sbase + j4;
        float4 hv = *(const float4*)&hs_t[c * TSTR + s4];
        float4 q0 = *(const float4*)&c0p[s4];
        float4 q1 = *(const float4*)&c1p[s4];
        float4 q2 = *(const float4*)&c2p[s4];
        float4 q3 = *(const float4*)&c3p[s4];
        acc0 += q0.x * hv.x + q0.y * hv.y + q0.z * hv.z + q0.w * hv.w;
        acc1 += q1.x * hv.x + q1.y * hv.y + q1.z * hv.z + q1.w * hv.w;
        acc2 += q2.x * hv.x + q2.y * hv.y + q2.z * hv.z + q2.w * hv.w;
        acc3 += q3.x * hv.x + q3.y * hv.y + q3.z * hv.z + q3.w * hv.w;
        den0 += (q0.x + q0.y) + (q0.z + q0.w);
        den1 += (q1.x + q1.y) + (q1.z + q1.w);
        den2 += (q2.x + q2.y) + (q2.z + q2.w);
        den3 += (q3.x + q3.y) + (q3.z + q3.w);
    }
    acc0 += __shfl_xor(acc0, 32);  den0 += __shfl_xor(den0, 32);
    acc1 += __shfl_xor(acc1, 32);  den1 += __shfl_xor(den1, 32);
    acc2 += __shfl_xor(acc2, 32);  den2 += __shfl_xor(den2, 32);
    acc3 += __shfl_xor(acc3, 32);  den3 += __shfl_xor(den3, 32);

    if (!last) {
        if (lane < 32) {
            float bv = bias[lane];
            size_t dbase = (size_t)g * NPG + part * DPB + wave * 4;
            if (actp[0]) h_out[(dbase + 0) * 32 + lane] = acc0 / den0 + bv;
            if (actp[1]) h_out[(dbase + 1) * 32 + lane] = acc1 / den1 + bv;
            if (actp[2]) h_out[(dbase + 2) * 32 + lane] = acc2 / den2 + bv;
            if (actp[3]) h_out[(dbase + 3) * 32 + lane] = acc3 / den3 + bv;
        }
    } else {
        // fused global_add_pool + linear + relu
        float* pw = &scratch[3000];      // [4][32], clear of coef region
        if (lane < 32) {
            float bv = bias[lane];
            float s = 0.f;
            if (actp[0]) s += acc0 / den0 + bv;
            if (actp[1]) s += acc1 / den1 + bv;
            if (actp[2]) s += acc2 / den2 + bv;
            if (actp[3]) s += acc3 / den3 + bv;
            pw[wave * 32 + lane] = s;
        }
        __syncthreads();
        if (t < 32) {
            float pc = pw[t] + pw[32 + t] + pw[64 + t] + pw[96 + t];
            float q = pc * linW[t];
            for (int off = 1; off < 32; off <<= 1) q += __shfl_xor(q, off);
            if (t == 0) {
                atomicAdd(&accG[g], q);
                __threadfence();
                int old = atomicAdd(&cntG[g], 1);
                if (old == 7) {
                    __threadfence();
                    float tot = atomicAdd(&accG[g], 0.f);
                    outp[g] = fmaxf(tot + linb[0], 0.f);
                }
            }
        }
    }
}

// ---------------------------------------------------------------------------
extern "C" void kernel_launch(void* const* d_in, const int* in_sizes, int n_in,
                              void* d_out, int out_size, void* d_ws, size_t ws_size,
                              hipStream_t stream) {
    // input order: x, edge_index, edge_attr, {W,as,ad,We,ae,b} x3, lin_W, lin_b
    const float* x    = (const float*)d_in[0];
    const float* ea   = (const float*)d_in[2];
    const float* W[3]  = {(const float*)d_in[3],  (const float*)d_in[9],  (const float*)d_in[15]};
    const float* as_[3]= {(const float*)d_in[4],  (const float*)d_in[10], (const float*)d_in[16]};
    const float* ad_[3]= {(const float*)d_in[5],  (const float*)d_in[11], (const float*)d_in[17]};
    const float* We[3] = {(const float*)d_in[6],  (const float*)d_in[12], (const float*)d_in[18]};
    const float* ae[3] = {(const float*)d_in[7],  (const float*)d_in[13], (const float*)d_in[19]};
    const float* b[3]  = {(const float*)d_in[8],  (const float*)d_in[14], (const float*)d_in[20]};
    const float* linW  = (const float*)d_in[21];
    const float* linb  = (const float*)d_in[22];
    float* out = (float*)d_out;

    float* ws   = (float*)d_ws;
    float* h0   = ws;                          // NTOT*32
    float* h1   = h0 + (size_t)NTOT * 32;      // NTOT*32
    float* accG = h1 + (size_t)NTOT * 32;      // BGR
    int*   cntG = (int*)(accG + BGR);          // BGR

    gat_fused<<<BGR * 8, 256, 0, stream>>>(x, 1, 0, 0,
                                           W[0], as_[0], ad_[0], We[0], ae[0],
                                           ea, b[0], linW, linb,
                                           h0, accG, cntG, out);
    gat_fused<<<BGR * 8, 256, 0, stream>>>(h0, 0, 0, 0,
                                           W[1], as_[1], ad_[1], We[1], ae[1],
                                           ea, b[1], linW, linb,
                                           h1, accG, cntG, out);
    gat_fused<<<BGR * 8, 256, 0, stream>>>(h1, 0, 1, 1,
                                           W[2], as_[2], ad_[2], We[2], ae[2],
                                           ea, b[2], linW, linb,
                                           h0, accG, cntG, out);
}

// Round 7
// 186.692 us; speedup vs baseline: 1.1045x; 1.1045x over previous
//
#include <hip/hip_runtime.h>
#include <hip/hip_bf16.h>

// Problem constants (fixed by the reference setup)
#define BGR  128          // graphs
#define NPG  111          // nodes per graph
#define EPG  (NPG*(NPG-1))// 12210 directed edges per graph
#define NTOT (BGR*NPG)    // 14208 nodes
#define PADW 112          // global row length (eatt rows, h_t rows)
#define PADT 113          // eatt LDS-internal pad (conflict-free scatter)
#define TSTR 113          // hs_t row stride in gat (coprime with 32)
#define HSTR 57           // hst row stride in projt (57%32=25, coprime)
#define DPB  14           // dsts per gat block (8 blocks per graph)

// ---------------------------------------------------------------------------
// Kernel 1: per-layer edge-attention scalar -> eatt[l][g][d][112] (r5 version).
// eatt[s->d] = ea.x*c0 + ea.y*c1, (c0,c1) = We @ ae; diag = rowmean (self-loop
// fill='mean' is linear). grid = 3*BGR blocks of 256.
__global__ void eatt_kernel(const float* __restrict__ ea,
                            const float* __restrict__ We0, const float* __restrict__ ae0,
                            const float* __restrict__ We1, const float* __restrict__ ae1,
                            const float* __restrict__ We2, const float* __restrict__ ae2,
                            float* __restrict__ eatt) {
    int l = blockIdx.x / BGR;
    int g = blockIdx.x % BGR;
    const float* We = (l == 0) ? We0 : ((l == 1) ? We1 : We2);
    const float* ae = (l == 0) ? ae0 : ((l == 1) ? ae1 : ae2);

    __shared__ float tile[NPG * PADT];
    __shared__ float cvec[2];
    int t = threadIdx.x;

    if (t < NPG) tile[t * PADT + t] = 0.f;   // diagonal = 0 so row-sum works
    if (t < 64) {
        int r = t >> 5, k = t & 31;
        float p = We[r * 32 + k] * ae[k];
        for (int off = 1; off < 32; off <<= 1) p += __shfl_xor(p, off);
        if (k == 0) cvec[r] = p;
    }
    __syncthreads();
    float c0 = cvec[0], c1 = cvec[1];

    const float* eg = ea + (size_t)g * EPG * 2;
    for (int e = t; e < EPG; e += 256) {
        float2 v = ((const float2*)eg)[e];
        int s = e / 110;
        int j = e - s * 110;
        int d = j + (j >= s ? 1 : 0);
        tile[d * PADT + s] = v.x * c0 + v.y * c1;  // never writes the diagonal
    }
    __syncthreads();

    if (t < NPG) {                 // diagonal = mean of incoming, zero shuffles
        float sum = 0.f;
        #pragma unroll 8
        for (int s = 0; s < NPG; s++) sum += tile[t * PADT + s];
        tile[t * PADT + t] = sum * (1.f / 110.f);
    }
    __syncthreads();

    float* out = eatt + (size_t)(l * BGR + g) * NPG * PADW;
    for (int i = t; i < NPG * PADW; i += 256) {
        int d = i / PADW, s = i - d * PADW;
        out[i] = tile[d * PADT + s];   // col 111 is garbage; never read
    }
}

// ---------------------------------------------------------------------------
// Kernel 2: per-layer projection, computed ONCE per graph (dedup vs r6's 8x).
// Writes h_t[g][32][112] (transposed, col 111 zeroed) + ass/ads[g][111].
// grid = 2*BGR blocks of 256; block = (graph, node-half 56/55).
__global__ __launch_bounds__(256) void
projt_kernel(const float* __restrict__ xin, int din1, int do_relu,
             const float* __restrict__ W,
             const float* __restrict__ as_w, const float* __restrict__ ad_w,
             float* __restrict__ h_t,        // [BGR][32][PADW]
             float* __restrict__ assG, float* __restrict__ adsG) {
    int g = blockIdx.x >> 1;
    int half = blockIdx.x & 1;
    int n0 = half * 56;
    int nn = half ? 55 : 56;
    int t = threadIdx.x;
    int c = t & 31, il = t >> 5;

    __shared__ float xl[56 * 32];
    __shared__ float hst[32 * HSTR];
    __shared__ float Ws[1024];
    __shared__ float asw[32], adw[32];

    if (din1) {
        if (t < nn) xl[t] = xin[g * NPG + n0 + t];
        if (t < 32) Ws[t] = W[t];
    } else {
        const float4* src = (const float4*)(xin + ((size_t)g * NPG + n0) * 32);
        for (int i = t; i < nn * 8; i += 256) ((float4*)xl)[i] = src[i];
        for (int i = t; i < 1024; i += 256) Ws[i] = W[i];
    }
    if (t < 32) { asw[t] = as_w[t]; adw[t] = ad_w[t]; }
    __syncthreads();

    for (int p = 0; p < 7; p++) {
        int sl = p * 8 + il;
        if (sl < nn) {
            float hv;
            if (din1) {
                hv = xl[sl] * Ws[c];
            } else {
                float acc = 0.f;
                const float4* row = (const float4*)&xl[sl * 32];
                #pragma unroll
                for (int k4 = 0; k4 < 8; k4++) {
                    float4 xv = row[k4];
                    if (do_relu) {
                        xv.x = fmaxf(xv.x, 0.f); xv.y = fmaxf(xv.y, 0.f);
                        xv.z = fmaxf(xv.z, 0.f); xv.w = fmaxf(xv.w, 0.f);
                    }
                    acc += xv.x * Ws[(k4 * 4 + 0) * 32 + c]
                         + xv.y * Ws[(k4 * 4 + 1) * 32 + c]
                         + xv.z * Ws[(k4 * 4 + 2) * 32 + c]
                         + xv.w * Ws[(k4 * 4 + 3) * 32 + c];
                }
                hv = acc;
            }
            hst[c * HSTR + sl] = hv;
        }
    }
    __syncthreads();

    // as/ad: thread-per-node column dots (lane stride 1, conflict-free)
    if (t < nn) {
        float sa = 0.f, sd = 0.f;
        #pragma unroll 8
        for (int cc = 0; cc < 32; cc++) {
            float hv = hst[cc * HSTR + t];
            sa += hv * asw[cc];
            sd += hv * adw[cc];
        }
        assG[g * NPG + n0 + t] = sa;
        adsG[g * NPG + n0 + t] = sd;
    }

    // h_t write: coalesced 56-float runs per channel row
    float* htg = h_t + (size_t)g * 32 * PADW;
    for (int i = t; i < 32 * 56; i += 256) {
        int cc = i / 56, sl = i - cc * 56;
        if (sl < nn) htg[cc * PADW + n0 + sl] = hst[cc * HSTR + sl];
    }
    if (half == 1 && t < 32) htg[t * PADW + 111] = 0.f;   // zero pad col
}

// ---------------------------------------------------------------------------
// Kernel 3: GAT attention + aggregation (proj precomputed); last layer fuses
// global_add_pool + linear + relu. grid = BGR*8 blocks of 256.
__global__ __launch_bounds__(256) void
gat_kernel(const float* __restrict__ h_t,   // [BGR][32][PADW]
           const float* __restrict__ assG, const float* __restrict__ adsG,
           const float* __restrict__ eatt_l,// [BGR][NPG][PADW]
           const float* __restrict__ bias,
           int zero_flag, int last,
           const float* __restrict__ linW, const float* __restrict__ linb,
           float* __restrict__ h_out,
           float* __restrict__ accG, int* __restrict__ cntG,
           float* __restrict__ outp) {
    int g = blockIdx.x >> 3;
    int part = blockIdx.x & 7;
    int t = threadIdx.x;
    int wave = t >> 6, lane = t & 63;
    int c = lane & 31;

    __shared__ float hs_t[32 * TSTR];     // transposed h
    __shared__ float coef[16 * PADW];     // per-wave rows (wave owns 4w..4w+3)
    __shared__ float ass[112], ads[112];
    __shared__ float pw[128];

    if (zero_flag && part == 0 && t == 0) { accG[g] = 0.f; cntG[g] = 0; }

    // ---- stage hs_t from h_t (coalesced float4 reads, b32 LDS writes) ----
    {
        const float4* ht4 = (const float4*)(h_t + (size_t)g * 32 * PADW);
        for (int i4 = t; i4 < 32 * 28; i4 += 256) {
            float4 v = ht4[i4];
            int cc = i4 / 28;
            int s4 = (i4 - cc * 28) * 4;
            float* dst = &hs_t[cc * TSTR + s4];
            dst[0] = v.x; dst[1] = v.y; dst[2] = v.z; dst[3] = v.w;
        }
    }
    if (t < NPG) { ass[t] = assG[g * NPG + t]; ads[t] = adsG[g * NPG + t]; }
    __syncthreads();

    // ---- scores: exp(leaky(.)), no reductions; coef per-wave ----
    bool actp[4];
    int sB = lane + 64;
    float erA[4], erB[4];
    #pragma unroll
    for (int p = 0; p < 4; p++) {
        int dl = wave * 4 + p;
        int d = part * DPB + dl;
        actp[p] = (dl < DPB) && (d < NPG);
        const float* er = eatt_l + ((size_t)g * NPG + d) * PADW;
        erA[p] = actp[p] ? er[lane] : 0.f;
        erB[p] = (actp[p] && sB < NPG) ? er[sB] : 0.f;
    }
    #pragma unroll
    for (int p = 0; p < 4; p++) {
        int dl = wave * 4 + p;
        int row = dl * PADW;
        if (actp[p]) {
            float add = ads[part * DPB + dl];
            float a1 = ass[lane] + add + erA[p];
            a1 = (a1 > 0.f) ? a1 : 0.2f * a1;
            coef[row + lane] = __expf(a1);
            if (sB < PADW) {
                float e2 = 0.f;
                if (sB < NPG) {
                    float a2 = ass[sB] + add + erB[p];
                    a2 = (a2 > 0.f) ? a2 : 0.2f * a2;
                    e2 = __expf(a2);
                }
                coef[row + sB] = e2;
            }
        } else {
            coef[row + lane] = 0.f;
            if (sB < PADW) coef[row + sB] = 0.f;
        }
    }
    // same-wave LDS write->read is ordered; no barrier needed

    // ---- aggregation + denominator (float4, broadcast coef reads) ----
    int sbase = (lane >> 5) * 56;          // half 0: s 0..55, half 1: 56..111
    const float* c0p = &coef[(wave * 4 + 0) * PADW];
    const float* c1p = &coef[(wave * 4 + 1) * PADW];
    const float* c2p = &coef[(wave * 4 + 2) * PADW];
    const float* c3p = &coef[(wave * 4 + 3) * PADW];
    float acc0 = 0.f, acc1 = 0.f, acc2 = 0.f, acc3 = 0.f;
    float den0 = 0.f, den1 = 0.f, den2 = 0.f, den3 = 0.f;
    #pragma unroll
    for (int j4 = 0; j4 < 56; j4 += 4) {
        int s4 = sbase + j4;
        float4 hv = *(const float4*)&hs_t[c * TSTR + s4];
        float4 q0 = *(const float4*)&c0p[s4];
        float4 q1 = *(const float4*)&c1p[s4];
        float4 q2 = *(const float4*)&c2p[s4];
        float4 q3 = *(const float4*)&c3p[s4];
        acc0 += q0.x * hv.x + q0.y * hv.y + q0.z * hv.z + q0.w * hv.w;
        acc1 += q1.x * hv.x + q1.y * hv.y + q1.z * hv.z + q1.w * hv.w;
        acc2 += q2.x * hv.x + q2.y * hv.y + q2.z * hv.z + q2.w * hv.w;
        acc3 += q3.x * hv.x + q3.y * hv.y + q3.z * hv.z + q3.w * hv.w;
        den0 += (q0.x + q0.y) + (q0.z + q0.w);
        den1 += (q1.x + q1.y) + (q1.z + q1.w);
        den2 += (q2.x + q2.y) + (q2.z + q2.w);
        den3 += (q3.x + q3.y) + (q3.z + q3.w);
    }
    acc0 += __shfl_xor(acc0, 32);  den0 += __shfl_xor(den0, 32);
    acc1 += __shfl_xor(acc1, 32);  den1 += __shfl_xor(den1, 32);
    acc2 += __shfl_xor(acc2, 32);  den2 += __shfl_xor(den2, 32);
    acc3 += __shfl_xor(acc3, 32);  den3 += __shfl_xor(den3, 32);

    if (!last) {
        if (lane < 32) {
            float bv = bias[lane];
            size_t dbase = (size_t)g * NPG + part * DPB + wave * 4;
            if (actp[0]) h_out[(dbase + 0) * 32 + lane] = acc0 / den0 + bv;
            if (actp[1]) h_out[(dbase + 1) * 32 + lane] = acc1 / den1 + bv;
            if (actp[2]) h_out[(dbase + 2) * 32 + lane] = acc2 / den2 + bv;
            if (actp[3]) h_out[(dbase + 3) * 32 + lane] = acc3 / den3 + bv;
        }
    } else {
        if (lane < 32) {
            float bv = bias[lane];
            float s = 0.f;
            if (actp[0]) s += acc0 / den0 + bv;
            if (actp[1]) s += acc1 / den1 + bv;
            if (actp[2]) s += acc2 / den2 + bv;
            if (actp[3]) s += acc3 / den3 + bv;
            pw[wave * 32 + lane] = s;
        }
        __syncthreads();
        if (t < 32) {
            float pc = pw[t] + pw[32 + t] + pw[64 + t] + pw[96 + t];
            float q = pc * linW[t];
            for (int off = 1; off < 32; off <<= 1) q += __shfl_xor(q, off);
            if (t == 0) {
                atomicAdd(&accG[g], q);
                __threadfence();
                int old = atomicAdd(&cntG[g], 1);
                if (old == 7) {
                    __threadfence();
                    float tot = atomicAdd(&accG[g], 0.f);
                    outp[g] = fmaxf(tot + linb[0], 0.f);
                }
            }
        }
    }
}

// ---------------------------------------------------------------------------
extern "C" void kernel_launch(void* const* d_in, const int* in_sizes, int n_in,
                              void* d_out, int out_size, void* d_ws, size_t ws_size,
                              hipStream_t stream) {
    // input order: x, edge_index, edge_attr, {W,as,ad,We,ae,b} x3, lin_W, lin_b
    const float* x    = (const float*)d_in[0];
    const float* ea   = (const float*)d_in[2];
    const float* W[3]  = {(const float*)d_in[3],  (const float*)d_in[9],  (const float*)d_in[15]};
    const float* as_[3]= {(const float*)d_in[4],  (const float*)d_in[10], (const float*)d_in[16]};
    const float* ad_[3]= {(const float*)d_in[5],  (const float*)d_in[11], (const float*)d_in[17]};
    const float* We[3] = {(const float*)d_in[6],  (const float*)d_in[12], (const float*)d_in[18]};
    const float* ae[3] = {(const float*)d_in[7],  (const float*)d_in[13], (const float*)d_in[19]};
    const float* b[3]  = {(const float*)d_in[8],  (const float*)d_in[14], (const float*)d_in[20]};
    const float* linW  = (const float*)d_in[21];
    const float* linb  = (const float*)d_in[22];
    float* out = (float*)d_out;

    float* ws   = (float*)d_ws;
    float* eatt = ws;                                   // 3*BGR*NPG*PADW
    float* h_t  = eatt + (size_t)3 * BGR * NPG * PADW;  // BGR*32*PADW
    float* h0   = h_t  + (size_t)BGR * 32 * PADW;       // NTOT*32
    float* h1   = h0   + (size_t)NTOT * 32;             // NTOT*32
    float* assG = h1   + (size_t)NTOT * 32;             // NTOT
    float* adsG = assG + (size_t)NTOT;                  // NTOT
    float* accG = adsG + (size_t)NTOT;                  // BGR
    int*   cntG = (int*)(accG + BGR);                   // BGR

    eatt_kernel<<<3 * BGR, 256, 0, stream>>>(ea, We[0], ae[0], We[1], ae[1],
                                             We[2], ae[2], eatt);

    projt_kernel<<<2 * BGR, 256, 0, stream>>>(x, 1, 0, W[0], as_[0], ad_[0],
                                              h_t, assG, adsG);
    gat_kernel<<<BGR * 8, 256, 0, stream>>>(h_t, assG, adsG,
                                            eatt + (size_t)0 * BGR * NPG * PADW,
                                            b[0], 1, 0, linW, linb,
                                            h0, accG, cntG, out);

    projt_kernel<<<2 * BGR, 256, 0, stream>>>(h0, 0, 0, W[1], as_[1], ad_[1],
                                              h_t, assG, adsG);
    gat_kernel<<<BGR * 8, 256, 0, stream>>>(h_t, assG, adsG,
                                            eatt + (size_t)1 * BGR * NPG * PADW,
                                            b[1], 0, 0, linW, linb,
                                            h1, accG, cntG, out);

    projt_kernel<<<2 * BGR, 256, 0, stream>>>(h1, 0, 1, W[2], as_[2], ad_[2],
                                              h_t, assG, adsG);
    gat_kernel<<<BGR * 8, 256, 0, stream>>>(h_t, assG, adsG,
                                            eatt + (size_t)2 * BGR * NPG * PADW,
                                            b[2], 0, 1, linW, linb,
                                            h1 /*unused*/, accG, cntG, out);
}

// Round 8
// 174.683 us; speedup vs baseline: 1.1805x; 1.0688x over previous
//
#include <hip/hip_runtime.h>
#include <hip/hip_bf16.h>

// Problem constants (fixed by the reference setup)
#define BGR  128          // graphs
#define NPG  111          // nodes per graph
#define EPG  (NPG*(NPG-1))// 12210 directed edges per graph
#define NTOT (BGR*NPG)    // 14208 nodes
#define PADW 112          // eatt row length [d][s]
#define PADT 113          // eatt LDS-internal pad (conflict-free scatter)
#define HSTR 57           // projt LDS row stride (coprime with 32)
#define KP   128          // padded K (source dim) for MFMA
#define ASTR 128          // assG/adsG per-graph stride (16B-aligned float4 reads)

typedef _Float16 half8 __attribute__((ext_vector_type(8)));
typedef float    f32x4 __attribute__((ext_vector_type(4)));

// ---------------------------------------------------------------------------
// Kernel 1 (unchanged, known-good): eatt[l][g][d][112]; diag = row-mean.
__global__ void eatt_kernel(const float* __restrict__ ea,
                            const float* __restrict__ We0, const float* __restrict__ ae0,
                            const float* __restrict__ We1, const float* __restrict__ ae1,
                            const float* __restrict__ We2, const float* __restrict__ ae2,
                            float* __restrict__ eatt) {
    int l = blockIdx.x / BGR;
    int g = blockIdx.x % BGR;
    const float* We = (l == 0) ? We0 : ((l == 1) ? We1 : We2);
    const float* ae = (l == 0) ? ae0 : ((l == 1) ? ae1 : ae2);

    __shared__ float tile[NPG * PADT];
    __shared__ float cvec[2];
    int t = threadIdx.x;

    if (t < NPG) tile[t * PADT + t] = 0.f;
    if (t < 64) {
        int r = t >> 5, k = t & 31;
        float p = We[r * 32 + k] * ae[k];
        for (int off = 1; off < 32; off <<= 1) p += __shfl_xor(p, off);
        if (k == 0) cvec[r] = p;
    }
    __syncthreads();
    float c0 = cvec[0], c1 = cvec[1];

    const float* eg = ea + (size_t)g * EPG * 2;
    for (int e = t; e < EPG; e += 256) {
        float2 v = ((const float2*)eg)[e];
        int s = e / 110;
        int j = e - s * 110;
        int d = j + (j >= s ? 1 : 0);
        tile[d * PADT + s] = v.x * c0 + v.y * c1;
    }
    __syncthreads();

    if (t < NPG) {
        float sum = 0.f;
        #pragma unroll 8
        for (int s = 0; s < NPG; s++) sum += tile[t * PADT + s];
        tile[t * PADT + t] = sum * (1.f / 110.f);
    }
    __syncthreads();

    float* out = eatt + (size_t)(l * BGR + g) * NPG * PADW;
    for (int i = t; i < NPG * PADW; i += 256) {
        int d = i / PADW, s = i - d * PADW;
        out[i] = tile[d * PADT + s];
    }
}

// ---------------------------------------------------------------------------
// Kernel 2: per-layer projection once per graph. Outputs:
//   h_t16 [g][32][KP] f16 (transposed, s>=111 zeroed)  -> gat B-fragments
//   assG/adsG [g][ASTR] fp32 attention dots
// grid = 2*BGR blocks of 256; block = (graph, node-half).
__global__ __launch_bounds__(256) void
projt_kernel(const float* __restrict__ xin, int din1, int do_relu,
             const float* __restrict__ W,
             const float* __restrict__ as_w, const float* __restrict__ ad_w,
             _Float16* __restrict__ h_t16,
             float* __restrict__ assG, float* __restrict__ adsG,
             int zero_acc, float* __restrict__ accG, int* __restrict__ cntG) {
    int g = blockIdx.x >> 1;
    int half = blockIdx.x & 1;
    int n0 = half * 56;
    int nn = half ? 55 : 56;
    int t = threadIdx.x;
    int c = t & 31, il = t >> 5;

    __shared__ float xl[56 * 32];
    __shared__ float hst[32 * HSTR];
    __shared__ float Ws[1024];
    __shared__ float asw[32], adw[32];

    if (din1) {
        if (t < nn) xl[t] = xin[g * NPG + n0 + t];
        if (t < 32) Ws[t] = W[t];
    } else {
        const float4* src = (const float4*)(xin + ((size_t)g * NPG + n0) * 32);
        for (int i = t; i < nn * 8; i += 256) ((float4*)xl)[i] = src[i];
        for (int i = t; i < 1024; i += 256) Ws[i] = W[i];
    }
    if (t < 32) { asw[t] = as_w[t]; adw[t] = ad_w[t]; }
    __syncthreads();

    for (int p = 0; p < 7; p++) {
        int sl = p * 8 + il;
        if (sl < nn) {
            float hv;
            if (din1) {
                hv = xl[sl] * Ws[c];
            } else {
                float acc = 0.f;
                const float4* row = (const float4*)&xl[sl * 32];
                #pragma unroll
                for (int k4 = 0; k4 < 8; k4++) {
                    float4 xv = row[k4];
                    if (do_relu) {
                        xv.x = fmaxf(xv.x, 0.f); xv.y = fmaxf(xv.y, 0.f);
                        xv.z = fmaxf(xv.z, 0.f); xv.w = fmaxf(xv.w, 0.f);
                    }
                    acc += xv.x * Ws[(k4 * 4 + 0) * 32 + c]
                         + xv.y * Ws[(k4 * 4 + 1) * 32 + c]
                         + xv.z * Ws[(k4 * 4 + 2) * 32 + c]
                         + xv.w * Ws[(k4 * 4 + 3) * 32 + c];
                }
                hv = acc;
            }
            hst[c * HSTR + sl] = hv;
        }
    }
    __syncthreads();

    // as/ad dots (thread-per-node, conflict-free columns)
    if (t < nn) {
        float sa = 0.f, sd = 0.f;
        #pragma unroll 8
        for (int cc = 0; cc < 32; cc++) {
            float hv = hst[cc * HSTR + t];
            sa += hv * asw[cc];
            sd += hv * adw[cc];
        }
        assG[g * ASTR + n0 + t] = sa;
        adsG[g * ASTR + n0 + t] = sd;
    }

    // h_t16 write (f16, transposed)
    _Float16* htg = h_t16 + (size_t)g * 32 * KP;
    for (int i = t; i < 32 * 56; i += 256) {
        int cc = i / 56, sl = i - cc * 56;
        if (sl < nn) htg[cc * KP + n0 + sl] = (_Float16)hst[cc * HSTR + sl];
    }
    if (half == 1) {
        for (int i = t; i < 32 * 17; i += 256) {
            int cc = i / 17, sl = 111 + (i - cc * 17);
            htg[cc * KP + sl] = (_Float16)0.f;
        }
        if (zero_acc && t == 0) { accG[g] = 0.f; cntG[g] = 0; }
    }
}

// ---------------------------------------------------------------------------
// Kernel 3: MFMA GAT. One 64-thread block per (graph, 16-dst M-tile).
// No LDS, no barriers. P built directly in A-layout (A[m=lane&15][k=quad*8+j]),
// H consumed as f16 B-fragments, den from f16-consistent per-lane sums.
// Last layer fuses global_add_pool + linear + relu (atomic ticket, 7 waves/graph).
__global__ __launch_bounds__(64) void
gat_mfma(const _Float16* __restrict__ h_t16,  // [BGR][32][KP]
         const float* __restrict__ assG, const float* __restrict__ adsG,
         const float* __restrict__ eatt_l,    // [BGR][NPG][PADW]
         const float* __restrict__ bias,
         int last,
         const float* __restrict__ linW, const float* __restrict__ linb,
         float* __restrict__ h_out,
         float* __restrict__ accG, int* __restrict__ cntG,
         float* __restrict__ outp) {
    int g  = blockIdx.x / 7;
    int mt = blockIdx.x % 7;             // dst tile: d = mt*16 .. mt*16+15
    int lane = threadIdx.x;
    int m = lane & 15;                   // A-row (local dst)
    int quad = lane >> 4;
    int d = mt * 16 + m;
    bool dok = (d < NPG);

    const float* assg = assG + g * ASTR;
    float adsv = dok ? adsG[g * ASTR + d] : 0.f;
    const float* er = eatt_l + ((size_t)g * NPG + d) * PADW;  // masked lanes read in-ws garbage
    const _Float16* hb = h_t16 + (size_t)g * 32 * KP;

    f32x4 acc0 = {0.f, 0.f, 0.f, 0.f};
    f32x4 acc1 = {0.f, 0.f, 0.f, 0.f};
    float den = 0.f;

    #pragma unroll
    for (int kc = 0; kc < 4; kc++) {
        int s0 = kc * 32 + quad * 8;     // this lane's 8 sources s0..s0+7
        float4 ea0 = *(const float4*)(er + s0);
        float4 ea1 = *(const float4*)(er + s0 + 4);
        float4 as0 = *(const float4*)(assg + s0);
        float4 as1 = *(const float4*)(assg + s0 + 4);
        half8 B0 = *(const half8*)(hb + (size_t)m * KP + s0);          // Nt=0: n=m
        half8 B1 = *(const half8*)(hb + (size_t)(16 + m) * KP + s0);   // Nt=1

        float ss[8] = {as0.x, as0.y, as0.z, as0.w, as1.x, as1.y, as1.z, as1.w};
        float ee[8] = {ea0.x, ea0.y, ea0.z, ea0.w, ea1.x, ea1.y, ea1.z, ea1.w};
        half8 A;
        #pragma unroll
        for (int j = 0; j < 8; j++) {
            int s = s0 + j;
            float a = ss[j] + adsv + ee[j];
            a = (a > 0.f) ? a : 0.2f * a;
            float p = (dok && (s < NPG)) ? __expf(a) : 0.f;
            _Float16 ph = (_Float16)p;
            A[j] = ph;
            den += (float)ph;            // f16-consistent denominator
        }
        acc0 = __builtin_amdgcn_mfma_f32_16x16x32_f16(A, B0, acc0, 0, 0, 0);
        acc1 = __builtin_amdgcn_mfma_f32_16x16x32_f16(A, B1, acc1, 0, 0, 0);
    }

    // full denominator for d = mt*16 + (lane&15): reduce across the 4 quads
    den += __shfl_xor(den, 16);
    den += __shfl_xor(den, 32);

    // epilogue: D row = quad*4+reg, col = lane&15 (C/D layout, verified)
    float bv0 = bias[m];
    float bv1 = bias[16 + m];
    if (!last) {
        #pragma unroll
        for (int r = 0; r < 4; r++) {
            int dr = mt * 16 + quad * 4 + r;
            float dn = __shfl(den, quad * 4 + r);   // lane (quad*4+r) holds den[dr]
            if (dr < NPG) {
                float inv = 1.f / dn;
                float* o = h_out + ((size_t)g * NPG + dr) * 32;
                o[m]      = acc0[r] * inv + bv0;
                o[16 + m] = acc1[r] * inv + bv1;
            }
        }
    } else {
        float lw0 = linW[m], lw1 = linW[16 + m];
        float p = 0.f;
        #pragma unroll
        for (int r = 0; r < 4; r++) {
            int dr = mt * 16 + quad * 4 + r;
            float dn = __shfl(den, quad * 4 + r);
            if (dr < NPG) {
                float inv = 1.f / dn;
                p += (acc0[r] * inv + bv0) * lw0 + (acc1[r] * inv + bv1) * lw1;
            }
        }
        #pragma unroll
        for (int off = 1; off < 64; off <<= 1) p += __shfl_xor(p, off);
        if (lane == 0) {
            atomicAdd(&accG[g], p);
            __threadfence();
            int old = atomicAdd(&cntG[g], 1);
            if (old == 6) {              // 7 waves per graph
                __threadfence();
                float tot = atomicAdd(&accG[g], 0.f);
                outp[g] = fmaxf(tot + linb[0], 0.f);
            }
        }
    }
}

// ---------------------------------------------------------------------------
extern "C" void kernel_launch(void* const* d_in, const int* in_sizes, int n_in,
                              void* d_out, int out_size, void* d_ws, size_t ws_size,
                              hipStream_t stream) {
    // input order: x, edge_index, edge_attr, {W,as,ad,We,ae,b} x3, lin_W, lin_b
    const float* x    = (const float*)d_in[0];
    const float* ea   = (const float*)d_in[2];
    const float* W[3]  = {(const float*)d_in[3],  (const float*)d_in[9],  (const float*)d_in[15]};
    const float* as_[3]= {(const float*)d_in[4],  (const float*)d_in[10], (const float*)d_in[16]};
    const float* ad_[3]= {(const float*)d_in[5],  (const float*)d_in[11], (const float*)d_in[17]};
    const float* We[3] = {(const float*)d_in[6],  (const float*)d_in[12], (const float*)d_in[18]};
    const float* ae[3] = {(const float*)d_in[7],  (const float*)d_in[13], (const float*)d_in[19]};
    const float* b[3]  = {(const float*)d_in[8],  (const float*)d_in[14], (const float*)d_in[20]};
    const float* linW  = (const float*)d_in[21];
    const float* linb  = (const float*)d_in[22];
    float* out = (float*)d_out;

    float* ws = (float*)d_ws;
    float*     eatt  = ws;                                    // 3*BGR*NPG*PADW fp32
    _Float16*  h_t16 = (_Float16*)(eatt + (size_t)3 * BGR * NPG * PADW); // BGR*32*KP f16
    float*     hbuf  = (float*)(h_t16 + (size_t)BGR * 32 * KP);          // NTOT*32 fp32
    float*     assG  = hbuf + (size_t)NTOT * 32;              // BGR*ASTR
    float*     adsG  = assG + (size_t)BGR * ASTR;             // BGR*ASTR
    float*     accG  = adsG + (size_t)BGR * ASTR;             // BGR
    int*       cntG  = (int*)(accG + BGR);                    // BGR

    eatt_kernel<<<3 * BGR, 256, 0, stream>>>(ea, We[0], ae[0], We[1], ae[1],
                                             We[2], ae[2], eatt);

    // layer 0
    projt_kernel<<<2 * BGR, 256, 0, stream>>>(x, 1, 0, W[0], as_[0], ad_[0],
                                              h_t16, assG, adsG, 0, accG, cntG);
    gat_mfma<<<7 * BGR, 64, 0, stream>>>(h_t16, assG, adsG,
                                         eatt + (size_t)0 * BGR * NPG * PADW,
                                         b[0], 0, linW, linb,
                                         hbuf, accG, cntG, out);
    // layer 1
    projt_kernel<<<2 * BGR, 256, 0, stream>>>(hbuf, 0, 0, W[1], as_[1], ad_[1],
                                              h_t16, assG, adsG, 0, accG, cntG);
    gat_mfma<<<7 * BGR, 64, 0, stream>>>(h_t16, assG, adsG,
                                         eatt + (size_t)1 * BGR * NPG * PADW,
                                         b[1], 0, linW, linb,
                                         hbuf, accG, cntG, out);
    // layer 2 (relu on input; fused pool+linear+relu)
    projt_kernel<<<2 * BGR, 256, 0, stream>>>(hbuf, 0, 1, W[2], as_[2], ad_[2],
                                              h_t16, assG, adsG, 1, accG, cntG);
    gat_mfma<<<7 * BGR, 64, 0, stream>>>(h_t16, assG, adsG,
                                         eatt + (size_t)2 * BGR * NPG * PADW,
                                         b[2], 1, linW, linb,
                                         hbuf, accG, cntG, out);
}

// Round 9
// 166.003 us; speedup vs baseline: 1.2422x; 1.0523x over previous
//
#include <hip/hip_runtime.h>
#include <hip/hip_bf16.h>

// Problem constants (fixed by the reference setup)
#define BGR  128           // graphs
#define NPG  111           // nodes per graph
#define EPG  (NPG*(NPG-1)) // 12210 directed edges per graph
#define H16S 136           // h16 row stride in halfs (272 B: 16B-aligned, 2-way banks)

typedef _Float16 half8 __attribute__((ext_vector_type(8)));
typedef float    f32x4 __attribute__((ext_vector_type(4)));

// ---------------------------------------------------------------------------
// ONE kernel: the whole 3-layer GAT + pool. One 512-thread block per graph;
// all inter-layer dependencies are intra-graph -> __syncthreads only.
// MFMA attention/aggregation structure carried over from round 8 (verified).
__global__ __launch_bounds__(512, 1) void
gnn_all(const float* __restrict__ x, const float* __restrict__ ea,
        const float* __restrict__ W0, const float* __restrict__ as0, const float* __restrict__ ad0,
        const float* __restrict__ We0, const float* __restrict__ ae0, const float* __restrict__ b0,
        const float* __restrict__ W1, const float* __restrict__ as1, const float* __restrict__ ad1,
        const float* __restrict__ We1, const float* __restrict__ ae1, const float* __restrict__ b1,
        const float* __restrict__ W2, const float* __restrict__ as2, const float* __restrict__ ad2,
        const float* __restrict__ We2, const float* __restrict__ ae2, const float* __restrict__ b2,
        const float* __restrict__ linW, const float* __restrict__ linb,
        float* __restrict__ out)
{
    int g = blockIdx.x;
    int t = threadIdx.x;
    int wave = t >> 6, lane = t & 63;
    int m = lane & 15, quad = lane >> 4;
    int c = t & 31, il = t >> 5;          // proj: 16 node slots x 32 channels

    __shared__ float     eattL[EPG];      // 48840 B: eatt[s*110 + col(d)]
    __shared__ _Float16  h16[32 * H16S];  // 8704 B: h transposed [c][s], f16
    __shared__ float     Ws[1024];
    __shared__ float     ass[112], ads[112], diag[112];
    __shared__ float     asw[32], adw[32], bsh[32];
    __shared__ float     xsh[112];
    __shared__ float     cv2[2];
    __shared__ float     pool7[8];

    // one-time init: x + zero h16 (pad cols s>=111 must be 0 forever)
    if (t < NPG) xsh[t] = x[g * NPG + t];
    for (int i = t; i < 32 * H16S; i += 512) h16[i] = (_Float16)0.f;

    const float4* eg4 = (const float4*)(ea + (size_t)g * EPG * 2);

    for (int l = 0; l < 3; l++) {
        const float* W  = (l == 0) ? W0  : ((l == 1) ? W1  : W2);
        const float* aS = (l == 0) ? as0 : ((l == 1) ? as1 : as2);
        const float* aD = (l == 0) ? ad0 : ((l == 1) ? ad1 : ad2);
        const float* Ne = (l == 0) ? We0 : ((l == 1) ? We1 : We2);
        const float* ae = (l == 0) ? ae0 : ((l == 1) ? ae1 : ae2);
        const float* bb = (l == 0) ? b0  : ((l == 1) ? b1  : b2);

        // ---- stage layer params ----
        if (l == 0) { if (t < 32) Ws[t] = W[t]; }
        else        { Ws[t] = W[t]; Ws[512 + t] = W[512 + t]; }
        if (t < 32) { asw[t] = aS[t]; adw[t] = aD[t]; bsh[t] = bb[t]; }
        if (t < 64) {
            int r = t >> 5, k = t & 31;
            float p = Ne[r * 32 + k] * ae[k];
            for (int off = 1; off < 32; off <<= 1) p += __shfl_xor(p, off);
            if (k == 0) cv2[r] = p;
        }
        __syncthreads();
        float c0 = cv2[0], c1 = cv2[1];

        // ---- stage eatt for this layer (fold c0,c1 at load) ----
        for (int i = t; i < EPG / 2; i += 512) {
            float4 v = eg4[i];
            float2 w;
            w.x = c0 * v.x + c1 * v.y;
            w.y = c0 * v.z + c1 * v.w;
            *(float2*)&eattL[2 * i] = w;
        }
        __syncthreads();

        // ---- diag (self-loop fill='mean': column mean) ----
        if (t < NPG) {
            float sum = 0.f;
            for (int s = 0; s < NPG; s++) {
                if (s != t) sum += eattL[s * 110 + t - (t > s ? 1 : 0)];
            }
            diag[t] = sum * (1.f / 110.f);
        }

        // ---- proj: h[s][c]; each row owned by one half-wave (lockstep-safe) ----
        for (int p = 0; p < 7; p++) {
            int s = p * 16 + il;
            if (s < NPG) {
                float hv;
                if (l == 0) {
                    hv = xsh[s] * Ws[c];
                } else {
                    float acc = 0.f;
                    #pragma unroll
                    for (int k = 0; k < 32; k++) {
                        float xv = (float)h16[k * H16S + s];   // broadcast read
                        if (l == 2) xv = fmaxf(xv, 0.f);       // relu on layer-2 input
                        acc += xv * Ws[k * 32 + c];
                    }
                    hv = acc;
                }
                h16[c * H16S + s] = (_Float16)hv;              // after all reads (lockstep)
            }
        }
        __syncthreads();

        // ---- ass/ads: thread-per-node column dots (2-way banks: free) ----
        if (t < NPG) {
            float sa = 0.f, sd = 0.f;
            #pragma unroll 8
            for (int cc = 0; cc < 32; cc++) {
                float hv = (float)h16[cc * H16S + t];
                sa += hv * asw[cc];
                sd += hv * adw[cc];
            }
            ass[t] = sa; ads[t] = sd;
        }
        __syncthreads();

        // ---- MFMA attention + aggregation (r8-verified layout) ----
        f32x4 acc0 = {0.f, 0.f, 0.f, 0.f};
        f32x4 acc1 = {0.f, 0.f, 0.f, 0.f};
        float den = 0.f;
        int mt = wave;                      // waves 0..6 = 7 M-tiles (112 dsts)
        int d = mt * 16 + m;
        bool dok = (wave < 7) && (d < NPG);
        if (wave < 7) {
            float adsv = dok ? ads[d] : 0.f;
            float dval = dok ? diag[d] : 0.f;
            #pragma unroll
            for (int kc = 0; kc < 4; kc++) {
                int s0 = kc * 32 + quad * 8;
                half8 A;
                #pragma unroll
                for (int j = 0; j < 8; j++) {
                    int s = s0 + j;
                    float p = 0.f;
                    if (dok && s < NPG) {
                        float ev = (s == d) ? dval
                                 : eattL[s * 110 + d - (d > s ? 1 : 0)];
                        float a = ass[s] + adsv + ev;
                        a = (a > 0.f) ? a : 0.2f * a;
                        p = __expf(a);
                    }
                    _Float16 ph = (_Float16)p;
                    A[j] = ph;
                    den += (float)ph;        // f16-consistent denominator
                }
                half8 B0 = *(const half8*)&h16[(size_t)m * H16S + s0];
                half8 B1 = *(const half8*)&h16[(size_t)(16 + m) * H16S + s0];
                acc0 = __builtin_amdgcn_mfma_f32_16x16x32_f16(A, B0, acc0, 0, 0, 0);
                acc1 = __builtin_amdgcn_mfma_f32_16x16x32_f16(A, B1, acc1, 0, 0, 0);
            }
            den += __shfl_xor(den, 16);
            den += __shfl_xor(den, 32);
        }
        __syncthreads();   // all B-fragment reads done before h16 is rewritten

        // ---- epilogue: new h into h16 (l<2) or fused pool+linear (l==2) ----
        if (wave < 7) {
            if (l < 2) {
                #pragma unroll
                for (int r = 0; r < 4; r++) {
                    int dr = mt * 16 + quad * 4 + r;
                    float dn = __shfl(den, quad * 4 + r);
                    if (dr < NPG) {
                        float inv = 1.f / dn;
                        h16[(size_t)m * H16S + dr]        = (_Float16)(acc0[r] * inv + bsh[m]);
                        h16[(size_t)(16 + m) * H16S + dr] = (_Float16)(acc1[r] * inv + bsh[16 + m]);
                    }
                }
            } else {
                float lw0 = linW[m], lw1 = linW[16 + m];
                float p = 0.f;
                #pragma unroll
                for (int r = 0; r < 4; r++) {
                    int dr = mt * 16 + quad * 4 + r;
                    float dn = __shfl(den, quad * 4 + r);
                    if (dr < NPG) {
                        float inv = 1.f / dn;
                        p += (acc0[r] * inv + bsh[m]) * lw0
                           + (acc1[r] * inv + bsh[16 + m]) * lw1;
                    }
                }
                #pragma unroll
                for (int off = 1; off < 64; off <<= 1) p += __shfl_xor(p, off);
                if (lane == 0) pool7[wave] = p;
            }
        }
        __syncthreads();
    }

    if (t == 0) {
        float s = 0.f;
        #pragma unroll
        for (int w = 0; w < 7; w++) s += pool7[w];
        out[g] = fmaxf(s + linb[0], 0.f);
    }
}

// ---------------------------------------------------------------------------
extern "C" void kernel_launch(void* const* d_in, const int* in_sizes, int n_in,
                              void* d_out, int out_size, void* d_ws, size_t ws_size,
                              hipStream_t stream) {
    // input order: x, edge_index, edge_attr, {W,as,ad,We,ae,b} x3, lin_W, lin_b
    const float* x    = (const float*)d_in[0];
    const float* ea   = (const float*)d_in[2];
    gnn_all<<<BGR, 512, 0, stream>>>(
        x, ea,
        (const float*)d_in[3],  (const float*)d_in[4],  (const float*)d_in[5],
        (const float*)d_in[6],  (const float*)d_in[7],  (const float*)d_in[8],
        (const float*)d_in[9],  (const float*)d_in[10], (const float*)d_in[11],
        (const float*)d_in[12], (const float*)d_in[13], (const float*)d_in[14],
        (const float*)d_in[15], (const float*)d_in[16], (const float*)d_in[17],
        (const float*)d_in[18], (const float*)d_in[19], (const float*)d_in[20],
        (const float*)d_in[21], (const float*)d_in[22],
        (float*)d_out);
}

// Round 10
// 146.657 us; speedup vs baseline: 1.4061x; 1.1319x over previous
//
#include <hip/hip_runtime.h>
#include <hip/hip_bf16.h>

// Problem constants (fixed by the reference setup)
#define BGR  128           // graphs
#define NPG  111           // nodes per graph
#define EPG  (NPG*(NPG-1)) // 12210 directed edges per graph
#define H16S 136           // h16 (transposed h) row stride in halfs, 16B-aligned
#define HRS  40            // hrow (row-major h) stride in halfs, 16B-aligned

typedef _Float16 half8 __attribute__((ext_vector_type(8)));
typedef float    f32x4 __attribute__((ext_vector_type(4)));

// ---------------------------------------------------------------------------
// ONE kernel: whole 3-layer GAT + pool. One 1024-thread block per graph.
// proj and attention-aggregation both run on MFMA; 3 barriers per layer.
__global__ __launch_bounds__(1024, 1) void
gnn_all(const float* __restrict__ x, const float* __restrict__ ea,
        const float* __restrict__ W0, const float* __restrict__ as0, const float* __restrict__ ad0,
        const float* __restrict__ We0, const float* __restrict__ ae0, const float* __restrict__ b0,
        const float* __restrict__ W1, const float* __restrict__ as1, const float* __restrict__ ad1,
        const float* __restrict__ We1, const float* __restrict__ ae1, const float* __restrict__ b1,
        const float* __restrict__ W2, const float* __restrict__ as2, const float* __restrict__ ad2,
        const float* __restrict__ We2, const float* __restrict__ ae2, const float* __restrict__ b2,
        const float* __restrict__ linW, const float* __restrict__ linb,
        float* __restrict__ out)
{
    int g = blockIdx.x;
    int t = threadIdx.x;
    int wave = t >> 6, lane = t & 63;
    int m = lane & 15, quad = lane >> 4;

    __shared__ float     eattL[EPG];        // 48840 B, eatt[s*110 + col(d)]
    __shared__ _Float16  h16[32 * H16S];    // 8704 B: h transposed [c][s]
    __shared__ _Float16  hrow[112 * HRS];   // 8960 B: h row-major [s][c] (k<32 used)
    __shared__ float     ass[112], ads[112], diag[112];
    __shared__ float     asw[32], adw[32], bsh[32];
    __shared__ float     pool7[8];

    // one-time init: pad cols of h16 (s>=111) and pad row of hrow must be 0
    for (int i = t; i < 32 * H16S; i += 1024) h16[i] = (_Float16)0.f;
    if (t < HRS) hrow[111 * HRS + t] = (_Float16)0.f;

    const float4* eg4 = (const float4*)(ea + (size_t)g * EPG * 2);

    for (int l = 0; l < 3; l++) {
        const float* W  = (l == 0) ? W0  : ((l == 1) ? W1  : W2);
        const float* aS = (l == 0) ? as0 : ((l == 1) ? as1 : as2);
        const float* aD = (l == 0) ? ad0 : ((l == 1) ? ad1 : ad2);
        const float* Ne = (l == 0) ? We0 : ((l == 1) ? We1 : We2);
        const float* av = (l == 0) ? ae0 : ((l == 1) ? ae1 : ae2);
        const float* bb = (l == 0) ? b0  : ((l == 1) ? b1  : b2);

        // ===== phase 1: eatt staging (+ per-wave c0,c1), proj-MFMA, params ====
        // c0,c1 = We @ ae, computed redundantly per wave (no LDS, no barrier)
        float red = Ne[(lane >> 5) * 32 + (lane & 31)] * av[lane & 31];
        #pragma unroll
        for (int off = 1; off < 32; off <<= 1) red += __shfl_xor(red, off);
        float c0 = __shfl(red, 0), c1 = __shfl(red, 32);

        for (int i = t; i < EPG / 2; i += 1024) {
            float4 v = eg4[i];
            float2 w2;
            w2.x = c0 * v.x + c1 * v.y;
            w2.y = c0 * v.z + c1 * v.w;
            *(float2*)&eattL[2 * i] = w2;
        }
        if (t < 32) { asw[t] = aS[t]; adw[t] = aD[t]; bsh[t] = bb[t]; }

        if (l == 0) {
            // proj is an outer product: h^T[c][s] = x[s] * W[c]
            for (int i = t; i < 32 * 112; i += 1024) {
                int c = i / 112, s = i - c * 112;
                float hv = (s < NPG) ? x[g * NPG + s] * W[c] : 0.f;
                h16[c * H16S + s] = (_Float16)hv;
            }
        } else if (wave < 14) {
            // proj-MFMA: h^T = W^T · hrow^T  (M=32 c, N=112 s, K=32), 1 MFMA/wave
            int ct = wave & 1, st = wave >> 1;   // ct in 0..1, st in 0..6
            int cb = ct * 16 + m;
            half8 A, B;
            #pragma unroll
            for (int j = 0; j < 8; j++) A[j] = (_Float16)W[(quad * 8 + j) * 32 + cb];
            B = *(const half8*)&hrow[(st * 16 + m) * HRS + quad * 8];
            if (l == 2) {                        // relu on layer-2 input
                #pragma unroll
                for (int j = 0; j < 8; j++)
                    B[j] = (B[j] > (_Float16)0.f) ? B[j] : (_Float16)0.f;
            }
            f32x4 D = {0.f, 0.f, 0.f, 0.f};
            D = __builtin_amdgcn_mfma_f32_16x16x32_f16(A, B, D, 0, 0, 0);
            #pragma unroll
            for (int r = 0; r < 4; r++)
                h16[(ct * 16 + quad * 4 + r) * H16S + st * 16 + m] = (_Float16)D[r];
        }
        __syncthreads();

        // ===== phase 2: ass/ads (waves 0-1) and diag (waves 2-3) in parallel ==
        if (t < NPG) {
            float sa = 0.f, sd = 0.f;
            #pragma unroll 8
            for (int cc = 0; cc < 32; cc++) {
                float hv = (float)h16[cc * H16S + t];
                sa += hv * asw[cc];
                sd += hv * adw[cc];
            }
            ass[t] = sa; ads[t] = sd;
        } else if (t >= 128 && t < 128 + NPG) {
            int d2 = t - 128;            // self-loop fill='mean' diag
            float sum = 0.f;
            #pragma unroll 8
            for (int s = 0; s < NPG; s++) {
                if (s != d2) sum += eattL[s * 110 + d2 - (d2 > s ? 1 : 0)];
            }
            diag[d2] = sum * (1.f / 110.f);
        }
        __syncthreads();

        // ===== phase 3: attention + aggregation MFMA (waves 0-6) ==============
        if (wave < 7) {
            f32x4 acc0 = {0.f, 0.f, 0.f, 0.f};
            f32x4 acc1 = {0.f, 0.f, 0.f, 0.f};
            float den = 0.f;
            int d = wave * 16 + m;
            bool dok = (d < NPG);
            float adsv = dok ? ads[d] : 0.f;
            float dval = dok ? diag[d] : 0.f;
            #pragma unroll
            for (int kc = 0; kc < 4; kc++) {
                int s0 = kc * 32 + quad * 8;
                half8 A;
                #pragma unroll
                for (int j = 0; j < 8; j++) {
                    int s = s0 + j;
                    float p = 0.f;
                    if (dok && s < NPG) {
                        float ev = (s == d) ? dval
                                 : eattL[s * 110 + d - (d > s ? 1 : 0)];
                        float a = ass[s] + adsv + ev;
                        a = (a > 0.f) ? a : 0.2f * a;
                        p = __expf(a);
                    }
                    _Float16 ph = (_Float16)p;
                    A[j] = ph;
                    den += (float)ph;    // f16-consistent denominator
                }
                half8 B0 = *(const half8*)&h16[(size_t)m * H16S + s0];
                half8 B1 = *(const half8*)&h16[(size_t)(16 + m) * H16S + s0];
                acc0 = __builtin_amdgcn_mfma_f32_16x16x32_f16(A, B0, acc0, 0, 0, 0);
                acc1 = __builtin_amdgcn_mfma_f32_16x16x32_f16(A, B1, acc1, 0, 0, 0);
            }
            den += __shfl_xor(den, 16);
            den += __shfl_xor(den, 32);

            if (l < 2) {                 // epilogue: new h -> hrow (row-major f16)
                #pragma unroll
                for (int r = 0; r < 4; r++) {
                    int dr = wave * 16 + quad * 4 + r;
                    float dn = __shfl(den, quad * 4 + r);
                    if (dr < NPG) {
                        float inv = 1.f / dn;
                        hrow[dr * HRS + m]      = (_Float16)(acc0[r] * inv + bsh[m]);
                        hrow[dr * HRS + 16 + m] = (_Float16)(acc1[r] * inv + bsh[16 + m]);
                    }
                }
            } else {                     // fused global_add_pool + linear
                float lw0 = linW[m], lw1 = linW[16 + m];
                float p = 0.f;
                #pragma unroll
                for (int r = 0; r < 4; r++) {
                    int dr = wave * 16 + quad * 4 + r;
                    float dn = __shfl(den, quad * 4 + r);
                    if (dr < NPG) {
                        float inv = 1.f / dn;
                        p += (acc0[r] * inv + bsh[m]) * lw0
                           + (acc1[r] * inv + bsh[16 + m]) * lw1;
                    }
                }
                #pragma unroll
                for (int off = 1; off < 64; off <<= 1) p += __shfl_xor(p, off);
                if (lane == 0) pool7[wave] = p;
            }
        }
        __syncthreads();
    }

    if (t == 0) {
        float s = 0.f;
        #pragma unroll
        for (int w = 0; w < 7; w++) s += pool7[w];
        out[g] = fmaxf(s + linb[0], 0.f);
    }
}

// ---------------------------------------------------------------------------
extern "C" void kernel_launch(void* const* d_in, const int* in_sizes, int n_in,
                              void* d_out, int out_size, void* d_ws, size_t ws_size,
                              hipStream_t stream) {
    // input order: x, edge_index, edge_attr, {W,as,ad,We,ae,b} x3, lin_W, lin_b
    const float* x  = (const float*)d_in[0];
    const float* ea = (const float*)d_in[2];
    gnn_all<<<BGR, 1024, 0, stream>>>(
        x, ea,
        (const float*)d_in[3],  (const float*)d_in[4],  (const float*)d_in[5],
        (const float*)d_in[6],  (const float*)d_in[7],  (const float*)d_in[8],
        (const float*)d_in[9],  (const float*)d_in[10], (const float*)d_in[11],
        (const float*)d_in[12], (const float*)d_in[13], (const float*)d_in[14],
        (const float*)d_in[15], (const float*)d_in[16], (const float*)d_in[17],
        (const float*)d_in[18], (const float*)d_in[19], (const float*)d_in[20],
        (const float*)d_in[21], (const float*)d_in[22],
        (float*)d_out);
}